// Round 6
// baseline (453.291 us; speedup 1.0000x reference)
//
#include <hip/hip_runtime.h>
#include <hip/hip_bf16.h>

typedef __bf16 bf16x8_t __attribute__((ext_vector_type(8)));
typedef float  f32x4_t  __attribute__((ext_vector_type(4)));

#define B_     2
#define L_     2048
#define D_     2048
#define H_     16
#define DH_    128
#define INNER_ 2048
#define M_     (B_ * L_)

// async global->LDS, 16B per lane. LDS dest must be wave-uniform base + lane*16.
__device__ __forceinline__ void gld_lds16(const void* g, void* l) {
    __builtin_amdgcn_global_load_lds(
        (const __attribute__((address_space(1))) void*)g,
        (__attribute__((address_space(3))) void*)l,
        16, 0, 0);
}

__device__ __forceinline__ unsigned short f2bf(float f) {
    __hip_bfloat16 h = __float2bfloat16(f);
    return *(unsigned short*)&h;
}
__device__ __forceinline__ float bf2f(unsigned short s) {
    return __uint_as_float(((unsigned)s) << 16);
}

// ---------------------------------------------------------------- cast f32 -> bf16
__global__ __launch_bounds__(256)
void k_cast(const float* __restrict__ in, unsigned short* __restrict__ out) {
    const size_t i = ((size_t)blockIdx.x * 256 + threadIdx.x) * 4;
    float4 v = *(const float4*)(in + i);
    ushort4 o;
    o.x = f2bf(v.x); o.y = f2bf(v.y); o.z = f2bf(v.z); o.w = f2bf(v.w);
    *(ushort4*)(out + i) = o;
}

// ---------------------------------------------------------------- fused 4x transpose+cast
__global__ __launch_bounds__(256)
void k_wtrans4(const float* __restrict__ w0, const float* __restrict__ w1,
               const float* __restrict__ w2, const float* __restrict__ w3,
               unsigned short* __restrict__ d0, unsigned short* __restrict__ d1,
               unsigned short* __restrict__ d2, unsigned short* __restrict__ d3) {
    const int z = blockIdx.z;
    const float* in = (z == 0) ? w0 : (z == 1) ? w1 : (z == 2) ? w2 : w3;
    unsigned short* out = (z == 0) ? d0 : (z == 1) ? d1 : (z == 2) ? d2 : d3;
    __shared__ unsigned short tile[32][33];
    const int t  = threadIdx.x;
    const int r  = t >> 3;
    const int c4 = (t & 7) << 2;
    const size_t ib = ((size_t)blockIdx.y * 32 + r) * 2048 + blockIdx.x * 32 + c4;
    float4 v = *(const float4*)(in + ib);
    tile[r][c4 + 0] = f2bf(v.x); tile[r][c4 + 1] = f2bf(v.y);
    tile[r][c4 + 2] = f2bf(v.z); tile[r][c4 + 3] = f2bf(v.w);
    __syncthreads();
    ushort4 o;
    o.x = tile[c4 + 0][r]; o.y = tile[c4 + 1][r];
    o.z = tile[c4 + 2][r]; o.w = tile[c4 + 3][r];
    const size_t ob = ((size_t)blockIdx.x * 32 + r) * 2048 + blockIdx.y * 32 + c4;
    *(ushort4*)(out + ob) = o;
}

// ---------------------------------------------------------------- GEMM core macro body
// Single combined smem (As|Bs) so epilogues can reuse the 16 KB after the K-loop.
#define GEMM_BODY(A_, Bt_, K_)                                                 \
    __shared__ __align__(16) __hip_bfloat16 SM[8192];                          \
    __hip_bfloat16* As = SM;                                                   \
    __hip_bfloat16* Bs = SM + 4096;                                            \
    const int t    = threadIdx.x;                                              \
    const int lane = t & 63;                                                   \
    const int wave = t >> 6;                                                   \
    const int quad = lane >> 4;                                                \
    const int l16  = lane & 15;                                                \
    const int wm   = (wave >> 1) * 64;                                         \
    const int wn   = (wave & 1) * 64;                                          \
    const int srow = t >> 2;                                                   \
    const int scol = (t & 3) << 3;                                             \
    const __hip_bfloat16* Ag = A_  + (size_t)(tileM + srow) * K_ + scol;       \
    const __hip_bfloat16* Bg = Bt_ + (size_t)(tileN + srow) * K_ + scol;       \
    __hip_bfloat16* Asl  = &As[t * 8];                                         \
    __hip_bfloat16* Asl2 = &As[2048 + t * 8];                                  \
    __hip_bfloat16* Bsl  = &Bs[t * 8];                                         \
    __hip_bfloat16* Bsl2 = &Bs[2048 + t * 8];                                  \
    const size_t rowskip = (size_t)64 * K_;                                    \
    f32x4_t acc[4][4];                                                         \
    _Pragma("unroll") for (int i = 0; i < 4; i++)                              \
        _Pragma("unroll") for (int j = 0; j < 4; j++)                          \
            acc[i][j] = (f32x4_t){0.f, 0.f, 0.f, 0.f};                         \
    for (int k0 = 0; k0 < K_; k0 += 32) {                                      \
        __syncthreads();                                                       \
        gld_lds16(Ag + k0,           Asl);                                     \
        gld_lds16(Ag + rowskip + k0, Asl2);                                    \
        gld_lds16(Bg + k0,           Bsl);                                     \
        gld_lds16(Bg + rowskip + k0, Bsl2);                                    \
        __syncthreads();                                                       \
        bf16x8_t af[4], bfr[4];                                                \
        _Pragma("unroll") for (int i = 0; i < 4; i++)                          \
            af[i] = *(const bf16x8_t*)&As[(wm + i * 16 + l16) * 32 + quad * 8];\
        _Pragma("unroll") for (int j = 0; j < 4; j++)                          \
            bfr[j] = *(const bf16x8_t*)&Bs[(wn + j * 16 + l16) * 32 + quad * 8];\
        _Pragma("unroll") for (int i = 0; i < 4; i++)                          \
            _Pragma("unroll") for (int j = 0; j < 4; j++)                      \
                acc[i][j] = __builtin_amdgcn_mfma_f32_16x16x32_bf16(           \
                    af[i], bfr[j], acc[i][j], 0, 0, 0);                        \
    }

// wo GEMM: f32 output to d_out
__global__ __launch_bounds__(256)
void k_gemm_bt_f32(const __hip_bfloat16* __restrict__ A,
                   const __hip_bfloat16* __restrict__ Bt,
                   const float* __restrict__ bias,
                   float* __restrict__ C,
                   int M, int N, int K) {
    const int tileM = blockIdx.x * 128;
    const int tileN = blockIdx.y * 128;
    GEMM_BODY(A, Bt, K)
#pragma unroll
    for (int i = 0; i < 4; i++)
#pragma unroll
        for (int r = 0; r < 4; r++) {
            const int m = tileM + wm + i * 16 + quad * 4 + r;
#pragma unroll
            for (int j = 0; j < 4; j++) {
                const int n = tileN + wn + j * 16 + l16;
                C[(size_t)m * N + n] = acc[i][j][r] + bias[n];
            }
        }
}

// fused QKV GEMM: Bt is [3*INNER][D] (wq^T|wk^T|wv^T), grid.y = 48.
// sel 0/1 -> q/k row-major. sel 2 -> v transposed into vT[(b*H+h)*DH+d][l],
// routed through the (dead) staging LDS in two 64x128 halves for coalesced
// 128B-row stores (round-5's direct scatter cost +23us in uncoalesced writes).
__global__ __launch_bounds__(256)
void k_gemm_qkv(const __hip_bfloat16* __restrict__ A,
                const __hip_bfloat16* __restrict__ Bt,
                const float* __restrict__ bq, const float* __restrict__ bk,
                const float* __restrict__ bv,
                __hip_bfloat16* __restrict__ qo, __hip_bfloat16* __restrict__ ko,
                __hip_bfloat16* __restrict__ vTo) {
    const int tileM = blockIdx.x * 128;
    const int tileN = blockIdx.y * 128;
    GEMM_BODY(A, Bt, D_)
    const int sel  = blockIdx.y >> 4;
    const int nbas = tileN - sel * INNER_;
    if (sel < 2) {
        const float* bias = (sel == 0) ? bq : bk;
        __hip_bfloat16* C = (sel == 0) ? qo : ko;
#pragma unroll
        for (int i = 0; i < 4; i++)
#pragma unroll
            for (int r = 0; r < 4; r++) {
                const int m = tileM + wm + i * 16 + quad * 4 + r;
#pragma unroll
                for (int j = 0; j < 4; j++) {
                    const int n = nbas + wn + j * 16 + l16;
                    C[(size_t)m * INNER_ + n] = __float2bfloat16(acc[i][j][r] + bias[n]);
                }
            }
    } else {
        const int bb = tileM >> 11;           // batch (128-row tile never straddles)
        const int hh = nbas >> 7;             // tile spans exactly one head
        const int l0 = tileM & (L_ - 1);
#pragma unroll 1
        for (int halfv = 0; halfv < 2; ++halfv) {
            __syncthreads();
            if ((wave >> 1) == halfv) {       // waves owning rows halfv*64..+63
#pragma unroll
                for (int i = 0; i < 4; i++) {
                    const int lo = i * 16 + quad * 4;          // local l 0..63
#pragma unroll
                    for (int j = 0; j < 4; j++) {
                        const int d = wn + j * 16 + l16;       // 0..127
                        const float bvn = bv[nbas + d];
                        ushort4 pk;
                        pk.x = f2bf(acc[i][j][0] + bvn);
                        pk.y = f2bf(acc[i][j][1] + bvn);
                        pk.z = f2bf(acc[i][j][2] + bvn);
                        pk.w = f2bf(acc[i][j][3] + bvn);
                        *(ushort4*)&SM[d * 64 + lo] = pk;      // [d][l] tile
                    }
                }
            }
            __syncthreads();
            // copy out: 128 d-rows x 64 l, 2 threads per row, 128B/row contiguous
            const int d  = t >> 1;
            const int lo = (t & 1) << 5;      // 0 or 32
            const __hip_bfloat16* src = &SM[d * 64 + lo];
            __hip_bfloat16* dst = vTo + ((size_t)(bb * H_ + hh) * DH_ + d) * L_
                                  + l0 + halfv * 64 + lo;
            *(uint4*)(dst)      = *(const uint4*)(src);
            *(uint4*)(dst + 8)  = *(const uint4*)(src + 8);
            *(uint4*)(dst + 16) = *(const uint4*)(src + 16);
            *(uint4*)(dst + 24) = *(const uint4*)(src + 24);
        }
    }
}

// ---------------------------------------------------------------- RMSNorm + RoPE (q&k fused)
__global__ __launch_bounds__(256)
void k_rmsrope2(__hip_bfloat16* __restrict__ qb, __hip_bfloat16* __restrict__ kb,
                const float* __restrict__ qn, const float* __restrict__ kn,
                const float* __restrict__ pcos, const float* __restrict__ psin,
                const float* __restrict__ lls, float qextra) {
    const int which = blockIdx.y;
    __hip_bfloat16* buf = which ? kb : qb;
    const float* w = which ? kn : qn;
    const int row = blockIdx.x;
    const int l   = row & (L_ - 1);
    const int t   = threadIdx.x;
    __hip_bfloat16* p = buf + (size_t)row * INNER_ + t * 8;

    float x[8];
    {
        const unsigned short* ps = (const unsigned short*)p;
        ushort4 a = *(const ushort4*)ps;
        ushort4 b = *(const ushort4*)(ps + 4);
        unsigned short s[8] = {a.x, a.y, a.z, a.w, b.x, b.y, b.z, b.w};
#pragma unroll
        for (int i = 0; i < 8; i++) x[i] = bf2f(s[i]);
    }
    float ss = 0.f;
#pragma unroll
    for (int i = 0; i < 8; i++) ss += x[i] * x[i];
#pragma unroll
    for (int off = 32; off >= 1; off >>= 1) ss += __shfl_down(ss, off);
    __shared__ float red[4];
    if ((t & 63) == 0) red[t >> 6] = ss;
    __syncthreads();
    ss = red[0] + red[1] + red[2] + red[3];
    const float rstd = rsqrtf(ss * (1.0f / (float)INNER_) + 1e-6f);

    const float scale = which ? 1.0f : (qextra * lls[l]);

    const float4 c4 = ((const float4*)(pcos + (size_t)l * (INNER_ / 2)))[t];
    const float4 s4 = ((const float4*)(psin + (size_t)l * (INNER_ / 2)))[t];
    const float cc[4] = {c4.x, c4.y, c4.z, c4.w};
    const float sn[4] = {s4.x, s4.y, s4.z, s4.w};
    const float4 w0 = ((const float4*)w)[t * 2];
    const float4 w1 = ((const float4*)w)[t * 2 + 1];
    const float ww[8] = {w0.x, w0.y, w0.z, w0.w, w1.x, w1.y, w1.z, w1.w};

    union { __hip_bfloat16 h[8]; uint4 u; } pk;
#pragma unroll
    for (int pi = 0; pi < 4; pi++) {
        const float y1 = x[pi * 2]     * rstd * ww[pi * 2];
        const float y2 = x[pi * 2 + 1] * rstd * ww[pi * 2 + 1];
        pk.h[pi * 2]     = __float2bfloat16((y1 * cc[pi] - y2 * sn[pi]) * scale);
        pk.h[pi * 2 + 1] = __float2bfloat16((y1 * sn[pi] + y2 * cc[pi]) * scale);
    }
    *(uint4*)p = pk.u;
}

// ---------------------------------------------------------------- attention
// Causal flash attention, S^T formulation, 512 threads = 8 waves x 16 q-rows.
__global__ __launch_bounds__(512)
void k_attn(const __hip_bfloat16* __restrict__ q,
            const __hip_bfloat16* __restrict__ k,
            const __hip_bfloat16* __restrict__ vT,
            __hip_bfloat16* __restrict__ o) {
    __shared__ __align__(16) __hip_bfloat16 Ks[64 * 128];   // [key][d] swizzled
    __shared__ __align__(16) __hip_bfloat16 Vs[128 * 64];   // [d][key] swizzled
    __shared__ __align__(16) __hip_bfloat16 Pt[8][16 * 72]; // [wave][qrow][key] stride 72

    const int p  = blockIdx.x;   // 0..7
    const int bh = blockIdx.y;
    const int b  = bh >> 4;
    const int h  = bh & 15;
    const int t = threadIdx.x, wave = t >> 6, lane = t & 63;
    const int quad = lane >> 4, l16 = lane & 15;

    const int kr = t >> 4;
    const int kc = ((t & 15) ^ (kr & 15)) << 3;
    const int vr = t >> 3;
    const int vc = ((t & 7) ^ (vr & 7)) << 3;
    const __hip_bfloat16* kbase = k  + (size_t)b * L_ * INNER_ + h * DH_;
    const __hip_bfloat16* vbase = vT + (size_t)bh * DH_ * L_;

    for (int half = 0; half < 2; ++half) {
        const int qt = half ? (15 - p) : p;
        const int rowbase = qt * 128 + wave * 16;

        bf16x8_t aq[4];
        {
            const size_t qoff = (size_t)(b * L_ + rowbase + l16) * INNER_ + h * DH_;
#pragma unroll
            for (int kk = 0; kk < 4; kk++)
                aq[kk] = *(const bf16x8_t*)(q + qoff + kk * 32 + quad * 8);
        }

        f32x4_t oacc[8];
#pragma unroll
        for (int jj = 0; jj < 8; jj++) oacc[jj] = (f32x4_t){0.f, 0.f, 0.f, 0.f};
        float m_ = -1e30f, l_ = 0.f;

        const int nkt = 2 * qt + 2;
        for (int kt = 0; kt < nkt; ++kt) {
            const int kv0 = kt * 64;
            __syncthreads();
            gld_lds16(kbase + (size_t)(kv0 + kr)      * INNER_ + kc, &Ks[t * 8]);
            gld_lds16(kbase + (size_t)(kv0 + 32 + kr) * INNER_ + kc, &Ks[4096 + t * 8]);
            gld_lds16(vbase + (size_t)vr        * L_ + kv0 + vc, &Vs[t * 8]);
            gld_lds16(vbase + (size_t)(64 + vr) * L_ + kv0 + vc, &Vs[4096 + t * 8]);
            __syncthreads();

            if (kv0 > rowbase + 15) continue;

            f32x4_t sacc[4];
#pragma unroll
            for (int tt = 0; tt < 4; tt++) sacc[tt] = (f32x4_t){0.f, 0.f, 0.f, 0.f};
#pragma unroll
            for (int kk = 0; kk < 4; kk++) {
                bf16x8_t kf[4];
#pragma unroll
                for (int tt = 0; tt < 4; tt++)
                    kf[tt] = *(const bf16x8_t*)&Ks[(tt * 16 + l16) * 128 + (((kk * 4 + quad) ^ l16) << 3)];
#pragma unroll
                for (int tt = 0; tt < 4; tt++)
                    sacc[tt] = __builtin_amdgcn_mfma_f32_16x16x32_bf16(
                        kf[tt], aq[kk], sacc[tt], 0, 0, 0);
            }

            if (kv0 + 63 > rowbase) {
                const int qrow = rowbase + l16;
#pragma unroll
                for (int tt = 0; tt < 4; tt++)
#pragma unroll
                    for (int r = 0; r < 4; r++)
                        if (kv0 + tt * 16 + quad * 4 + r > qrow) sacc[tt][r] = -1e30f;
            }

            float mx = sacc[0][0];
#pragma unroll
            for (int tt = 0; tt < 4; tt++)
#pragma unroll
                for (int r = 0; r < 4; r++) mx = fmaxf(mx, sacc[tt][r]);
            mx = fmaxf(mx, __shfl_xor(mx, 16));
            mx = fmaxf(mx, __shfl_xor(mx, 32));
            const float mnew = fmaxf(m_, mx);
            const float alpha = exp2f(m_ - mnew);
            m_ = mnew;

            float ls = 0.f;
#pragma unroll
            for (int tt = 0; tt < 4; tt++) {
                ushort4 pk;
                float p0 = exp2f(sacc[tt][0] - mnew);
                float p1 = exp2f(sacc[tt][1] - mnew);
                float p2 = exp2f(sacc[tt][2] - mnew);
                float p3 = exp2f(sacc[tt][3] - mnew);
                ls += (p0 + p1) + (p2 + p3);
                pk.x = f2bf(p0); pk.y = f2bf(p1); pk.z = f2bf(p2); pk.w = f2bf(p3);
                *(ushort4*)&Pt[wave][l16 * 72 + tt * 16 + quad * 4] = pk;
            }
            ls += __shfl_xor(ls, 16);
            ls += __shfl_xor(ls, 32);
            l_ = l_ * alpha + ls;
#pragma unroll
            for (int jj = 0; jj < 8; jj++) {
                oacc[jj][0] *= alpha; oacc[jj][1] *= alpha;
                oacc[jj][2] *= alpha; oacc[jj][3] *= alpha;
            }

#pragma unroll
            for (int kk2 = 0; kk2 < 2; kk2++) {
                bf16x8_t pf = *(const bf16x8_t*)&Pt[wave][l16 * 72 + kk2 * 32 + quad * 8];
#pragma unroll
                for (int jj = 0; jj < 8; jj++) {
                    bf16x8_t vf = *(const bf16x8_t*)
                        &Vs[(jj * 16 + l16) * 64 + (((kk2 * 4 + quad) ^ (l16 & 7)) << 3)];
                    oacc[jj] = __builtin_amdgcn_mfma_f32_16x16x32_bf16(vf, pf, oacc[jj], 0, 0, 0);
                }
            }
        }

        {
            const float inv = 1.0f / l_;
            __hip_bfloat16* orow = o + (size_t)(b * L_ + rowbase + l16) * INNER_ + h * DH_;
#pragma unroll
            for (int jj = 0; jj < 8; jj++) {
                ushort4 pk;
                pk.x = f2bf(oacc[jj][0] * inv);
                pk.y = f2bf(oacc[jj][1] * inv);
                pk.z = f2bf(oacc[jj][2] * inv);
                pk.w = f2bf(oacc[jj][3] * inv);
                *(ushort4*)(orow + jj * 16 + quad * 4) = pk;
            }
        }
    }
}

// ---------------------------------------------------------------- launch
extern "C" void kernel_launch(void* const* d_in, const int* in_sizes, int n_in,
                              void* d_out, int out_size, void* d_ws, size_t ws_size,
                              hipStream_t stream) {
    const float* x      = (const float*)d_in[0];
    const float* pe_cos = (const float*)d_in[1];
    const float* pe_sin = (const float*)d_in[2];
    const float* lls    = (const float*)d_in[3];
    const float* wq     = (const float*)d_in[4];
    const float* bq     = (const float*)d_in[5];
    const float* wk     = (const float*)d_in[6];
    const float* bk     = (const float*)d_in[7];
    const float* wv     = (const float*)d_in[8];
    const float* bv     = (const float*)d_in[9];
    const float* qn     = (const float*)d_in[10];
    const float* kn     = (const float*)d_in[11];
    const float* wo     = (const float*)d_in[12];
    const float* bo     = (const float*)d_in[13];

    char* ws = (char*)d_ws;
    const size_t SZ_W = (size_t)D_ * INNER_ * 2;   // 8 MB (bf16)
    const size_t SZ_M = (size_t)M_ * INNER_ * 2;   // 16 MB (bf16)
    __hip_bfloat16* xb     = (__hip_bfloat16*)ws;  ws += SZ_M;
    __hip_bfloat16* wqkvT  = (__hip_bfloat16*)ws;  ws += 3 * SZ_W;  // [6144][2048]
    __hip_bfloat16* woT    = (__hip_bfloat16*)ws;  ws += SZ_W;
    __hip_bfloat16* qb     = (__hip_bfloat16*)ws;  ws += SZ_M;
    __hip_bfloat16* kb     = (__hip_bfloat16*)ws;  ws += SZ_M;
    __hip_bfloat16* vT     = (__hip_bfloat16*)ws;  ws += SZ_M;
    __hip_bfloat16* ab     = (__hip_bfloat16*)ws;  ws += SZ_M;
    (void)in_sizes; (void)n_in; (void)out_size; (void)ws_size;

    const dim3 tb(256);

    // 0. cast x to bf16
    k_cast<<<(M_ * D_) / 1024, tb, 0, stream>>>(x, (unsigned short*)xb);

    // 1. all 4 weight transpose+casts in one dispatch
    k_wtrans4<<<dim3(64, 64, 4), tb, 0, stream>>>(
        wq, wk, wv, wo,
        (unsigned short*)wqkvT,
        (unsigned short*)(wqkvT + (size_t)INNER_ * D_),
        (unsigned short*)(wqkvT + 2 * (size_t)INNER_ * D_),
        (unsigned short*)woT);

    // 2. fused QKV projection; v transposed via LDS (coalesced stores)
    k_gemm_qkv<<<dim3(M_ / 128, 48), tb, 0, stream>>>(xb, wqkvT, bq, bk, bv, qb, kb, vT);

    // 3. RMSNorm + RoPE for q and k in one dispatch
    const float qextra = 0.08838834764831843f /* rsqrt(128) */ * 1.4426950408889634f /* log2 e */;
    k_rmsrope2<<<dim3(M_, 2), tb, 0, stream>>>(qb, kb, qn, kn, pe_cos, pe_sin, lls, qextra);

    // 4. causal flash attention (S^T formulation, 8 waves/block)
    k_attn<<<dim3(8, B_ * H_), dim3(512), 0, stream>>>(qb, kb, vT, ab);

    // 5. output projection -> d_out (f32)
    k_gemm_bt_f32<<<dim3(M_ / 128, D_ / 128), tb, 0, stream>>>(ab, woT, bo, (float*)d_out, M_, D_, INNER_);
}